// Round 11
// baseline (362.251 us; speedup 1.0000x reference)
//
#include <hip/hip_runtime.h>
#include <hip/hip_bf16.h>
#include <hip/hip_cooperative_groups.h>
#include <math.h>

namespace cg = cooperative_groups;

typedef __bf16 bf16_t;
typedef __bf16 bf16x8 __attribute__((ext_vector_type(8)));
typedef __bf16 bf16x4 __attribute__((ext_vector_type(4)));
typedef float  f32x4  __attribute__((ext_vector_type(4)));

#define L_DIM 2048
#define D_DIM 1024
#define H_DIM 16
#define M_DIM 4096
#define KTOP 409
#define SLOTS 448    // 7 * 64, padded (sel = -1 beyond KTOP)
#define KSPLIT 8
#define KCHUNK 256   // L_DIM / KSPLIT
#define NBLK 512     // cooperative grid: 512 blocks x 256 thr = 2 blocks/CU

struct FusedArgs {
  const float *x, *Wq, *bq, *Wk, *bk, *Wv, *bv, *Wo, *bo;
  bf16_t *xhi, *xlo, *Wqhi, *Wqlo, *Wkb, *Wvb, *Wob;
  bf16_t *Qhi, *Khi, *VThi;
  float *norms;
  int *sel, *slotmap;
  float *Ol;
  bf16_t *Oo, *AOhi;
  float *out;
};

__device__ __forceinline__ void split2(float a, bf16_t& h, bf16_t& l) {
  h = (bf16_t)a;
  l = (bf16_t)(a - (float)h);
}

// async global -> LDS, 16B per lane; lds ptr must be wave-uniform (m104/m108)
__device__ __forceinline__ void gld16(const bf16_t* g, bf16_t* l) {
  __builtin_amdgcn_global_load_lds(
      (const __attribute__((address_space(1))) void*)g,
      (__attribute__((address_space(3))) void*)l, 16, 0, 0);
}

#define STAGE_TILE128(src, dst)                                               \
  {                                                                           \
    const int seg0 = wave * 2;                                                \
    const int r0 = seg0 * 16 + (lane >> 2);                                   \
    const int c0 = (lane & 3) * 8;                                            \
    gld16((src) + (size_t)r0 * D_DIM + c0, (dst) + seg0 * 512);               \
    gld16((src) + (size_t)(r0 + 16) * D_DIM + c0, (dst) + (seg0 + 1) * 512);  \
  }

#define STAGE_TILE64(src, dst)                                                \
  {                                                                           \
    const int r0 = wave * 16 + (lane >> 2);                                   \
    const int c0 = (lane & 3) * 8;                                            \
    gld16((src) + (size_t)r0 * D_DIM + c0, (dst) + wave * 512);               \
  }

// ===========================================================================
// Shared device-side stage bodies (used by both the fused cooperative kernel
// and the multi-kernel fallback wrappers). All bodies are R8-proven.
// ===========================================================================

__device__ void prep_body(const float* x, const float* Wq, const float* Wk,
                          const float* Wv, const float* Wo,
                          bf16_t* xhi, bf16_t* xlo, bf16_t* Wqhi, bf16_t* Wqlo,
                          bf16_t* Wkb, bf16_t* Wvb, bf16_t* Wob,
                          int i) {
  const int XV = (M_DIM * D_DIM) / 4;
  const int WV = (D_DIM * D_DIM) / 4;
  if (i < XV) {
    f32x4 v = ((const f32x4*)x)[i];
    bf16x4 h, l;
    #pragma unroll
    for (int j = 0; j < 4; ++j) { bf16_t hh, ll; split2(v[j], hh, ll); h[j] = hh; l[j] = ll; }
    ((bf16x4*)xhi)[i] = h;
    ((bf16x4*)xlo)[i] = l;
  } else if (i < XV + WV) {
    int j0 = i - XV;
    f32x4 v = ((const f32x4*)Wq)[j0];
    bf16x4 h, l;
    #pragma unroll
    for (int j = 0; j < 4; ++j) { bf16_t hh, ll; split2(v[j], hh, ll); h[j] = hh; l[j] = ll; }
    ((bf16x4*)Wqhi)[j0] = h;
    ((bf16x4*)Wqlo)[j0] = l;
  } else if (i < XV + 2 * WV) {
    int j0 = i - XV - WV;
    f32x4 v = ((const f32x4*)Wk)[j0];
    bf16x4 h;
    #pragma unroll
    for (int j = 0; j < 4; ++j) h[j] = (bf16_t)v[j];
    ((bf16x4*)Wkb)[j0] = h;
  } else if (i < XV + 3 * WV) {
    int j0 = i - XV - 2 * WV;
    f32x4 v = ((const f32x4*)Wv)[j0];
    bf16x4 h;
    #pragma unroll
    for (int j = 0; j < 4; ++j) h[j] = (bf16_t)v[j];
    ((bf16x4*)Wvb)[j0] = h;
  } else {
    int j0 = i - XV - 3 * WV;
    f32x4 v = ((const f32x4*)Wo)[j0];
    bf16x4 h;
    #pragma unroll
    for (int j = 0; j < 4; ++j) h[j] = (bf16_t)v[j];
    ((bf16x4*)Wob)[j0] = h;
  }
}

__device__ void gemm_body(const bf16_t* xhi, const bf16_t* xlo,
                          const bf16_t* Wqhi, const bf16_t* Wqlo,
                          const bf16_t* Wkb, const bf16_t* Wvb,
                          const float* bq, const float* bk, const float* bv,
                          bf16_t* Qhi, bf16_t* Khi, bf16_t* VThi, float* norms,
                          int z, int idx, char* smem_raw) {
  const int n0   = (idx & 7) * 128;
  const int row0 = (idx >> 3) * 128;

  bf16_t* sm0 = (bf16_t*)smem_raw;
  bf16_t* sm1 = (bf16_t*)(smem_raw + 8192);
  bf16_t* sm2 = (bf16_t*)(smem_raw + 16384);
  bf16_t* sm3 = (bf16_t*)(smem_raw + 24576);

  const int tid  = threadIdx.x;
  const int lane = tid & 63;
  const int wave = tid >> 6;
  const int wr = wave >> 1, wc = wave & 1;
  const int lm = lane & 15, quad = lane >> 4;

  const f32x4 vzero = {0.f, 0.f, 0.f, 0.f};
  f32x4 acc[4][4];
  #pragma unroll
  for (int mi = 0; mi < 4; ++mi)
    #pragma unroll
    for (int ni = 0; ni < 4; ++ni) acc[mi][ni] = vzero;

  if (z == 0) {
    for (int k0 = 0; k0 < D_DIM; k0 += 32) {
      __syncthreads();
      STAGE_TILE128(xhi  + (size_t)row0 * D_DIM + k0, sm0);
      STAGE_TILE128(xlo  + (size_t)row0 * D_DIM + k0, sm1);
      STAGE_TILE128(Wqhi + (size_t)n0   * D_DIM + k0, sm2);
      STAGE_TILE128(Wqlo + (size_t)n0   * D_DIM + k0, sm3);
      __syncthreads();
      bf16x8 afh[4], afl[4], bfh[4], bfl[4];
      #pragma unroll
      for (int mi = 0; mi < 4; ++mi) {
        afh[mi] = *reinterpret_cast<const bf16x8*>(&sm0[(wr * 64 + mi * 16 + lm) * 32 + quad * 8]);
        afl[mi] = *reinterpret_cast<const bf16x8*>(&sm1[(wr * 64 + mi * 16 + lm) * 32 + quad * 8]);
      }
      #pragma unroll
      for (int ni = 0; ni < 4; ++ni) {
        bfh[ni] = *reinterpret_cast<const bf16x8*>(&sm2[(wc * 64 + ni * 16 + lm) * 32 + quad * 8]);
        bfl[ni] = *reinterpret_cast<const bf16x8*>(&sm3[(wc * 64 + ni * 16 + lm) * 32 + quad * 8]);
      }
      #pragma unroll
      for (int mi = 0; mi < 4; ++mi)
        #pragma unroll
        for (int ni = 0; ni < 4; ++ni) {
          acc[mi][ni] = __builtin_amdgcn_mfma_f32_16x16x32_bf16(afh[mi], bfh[ni], acc[mi][ni], 0, 0, 0);
          acc[mi][ni] = __builtin_amdgcn_mfma_f32_16x16x32_bf16(afh[mi], bfl[ni], acc[mi][ni], 0, 0, 0);
          acc[mi][ni] = __builtin_amdgcn_mfma_f32_16x16x32_bf16(afl[mi], bfh[ni], acc[mi][ni], 0, 0, 0);
        }
    }

    float bvv[4];
    #pragma unroll
    for (int ni = 0; ni < 4; ++ni) bvv[ni] = bq[n0 + wc * 64 + ni * 16 + lm];
    #pragma unroll
    for (int mi = 0; mi < 4; ++mi)
      #pragma unroll
      for (int ni = 0; ni < 4; ++ni)
        #pragma unroll
        for (int r = 0; r < 4; ++r) acc[mi][ni][r] += bvv[ni];

    const int h = (n0 + wc * 64) >> 6;
    #pragma unroll
    for (int mi = 0; mi < 4; ++mi)
      #pragma unroll
      for (int r = 0; r < 4; ++r) {
        float s = 0.f;
        #pragma unroll
        for (int ni = 0; ni < 4; ++ni) { float v = acc[mi][ni][r]; s += v * v; }
        s += __shfl_xor(s, 1); s += __shfl_xor(s, 2);
        s += __shfl_xor(s, 4); s += __shfl_xor(s, 8);
        if (lm == 0) {
          int row = row0 + wr * 64 + mi * 16 + quad * 4 + r;
          int bb = row >> 11, ll = row & (L_DIM - 1);
          norms[(bb * H_DIM + h) * L_DIM + ll] = s;
        }
      }

    #pragma unroll
    for (int mi = 0; mi < 4; ++mi)
      #pragma unroll
      for (int r = 0; r < 4; ++r) {
        int row = row0 + wr * 64 + mi * 16 + quad * 4 + r;
        #pragma unroll
        for (int ni = 0; ni < 4; ++ni)
          Qhi[(size_t)row * D_DIM + n0 + wc * 64 + ni * 16 + lm] = (bf16_t)acc[mi][ni][r];
      }
  } else {
    const bf16_t* W = (z == 1) ? Wkb : Wvb;
    for (int k0 = 0; k0 < D_DIM; k0 += 32) {
      __syncthreads();
      STAGE_TILE128(xhi + (size_t)row0 * D_DIM + k0, sm0);
      STAGE_TILE128(W   + (size_t)n0   * D_DIM + k0, sm2);
      __syncthreads();
      bf16x8 af[4], bfr[4];
      #pragma unroll
      for (int mi = 0; mi < 4; ++mi)
        af[mi] = *reinterpret_cast<const bf16x8*>(&sm0[(wr * 64 + mi * 16 + lm) * 32 + quad * 8]);
      #pragma unroll
      for (int ni = 0; ni < 4; ++ni)
        bfr[ni] = *reinterpret_cast<const bf16x8*>(&sm2[(wc * 64 + ni * 16 + lm) * 32 + quad * 8]);
      #pragma unroll
      for (int mi = 0; mi < 4; ++mi)
        #pragma unroll
        for (int ni = 0; ni < 4; ++ni)
          acc[mi][ni] = __builtin_amdgcn_mfma_f32_16x16x32_bf16(af[mi], bfr[ni], acc[mi][ni], 0, 0, 0);
    }

    const float* bias = (z == 1) ? bk : bv;
    float bvv[4];
    #pragma unroll
    for (int ni = 0; ni < 4; ++ni) bvv[ni] = bias[n0 + wc * 64 + ni * 16 + lm];
    #pragma unroll
    for (int mi = 0; mi < 4; ++mi)
      #pragma unroll
      for (int ni = 0; ni < 4; ++ni)
        #pragma unroll
        for (int r = 0; r < 4; ++r) acc[mi][ni][r] += bvv[ni];

    if (z == 1) {
      #pragma unroll
      for (int mi = 0; mi < 4; ++mi)
        #pragma unroll
        for (int r = 0; r < 4; ++r) {
          int row = row0 + wr * 64 + mi * 16 + quad * 4 + r;
          #pragma unroll
          for (int ni = 0; ni < 4; ++ni)
            Khi[(size_t)row * D_DIM + n0 + wc * 64 + ni * 16 + lm] = (bf16_t)acc[mi][ni][r];
        }
    } else {
      #pragma unroll
      for (int mi = 0; mi < 4; ++mi) {
        int rbase = row0 + wr * 64 + mi * 16 + quad * 4;
        int bb = rbase >> 11, l0 = rbase & (L_DIM - 1);
        #pragma unroll
        for (int ni = 0; ni < 4; ++ni) {
          int col = n0 + wc * 64 + ni * 16 + lm;
          bf16x4 wv;
          #pragma unroll
          for (int r = 0; r < 4; ++r) wv[r] = (bf16_t)acc[mi][ni][r];
          *reinterpret_cast<bf16x4*>(&VThi[((size_t)(bb * D_DIM + col)) * L_DIM + l0]) = wv;
        }
      }
    }
  }
}

// bitonic top-409 (norm desc, idx asc) — exact lax.top_k set; NT = blockDim.
__device__ void topk_body(const float* norms, int* sel, int* slotmap,
                          int bh, float* val, int* idx, int NT) {
  const int t = threadIdx.x;
  for (int i = t; i < L_DIM; i += NT) {
    val[i] = norms[bh * L_DIM + i];
    idx[i] = i;
    slotmap[bh * L_DIM + i] = -1;
  }
  __syncthreads();
  for (int k = 2; k <= L_DIM; k <<= 1) {
    for (int j = k >> 1; j > 0; j >>= 1) {
      for (int i = t; i < L_DIM; i += NT) {
        int ixj = i ^ j;
        if (ixj > i) {
          float v1 = val[i], v2 = val[ixj];
          int   i1 = idx[i], i2 = idx[ixj];
          bool up = ((i & k) == 0);
          bool sw = up ? ((v2 > v1) || (v2 == v1 && i2 < i1))
                       : ((v1 > v2) || (v1 == v2 && i1 < i2));
          if (sw) { val[i] = v2; val[ixj] = v1; idx[i] = i2; idx[ixj] = i1; }
        }
      }
      __syncthreads();
    }
  }
  for (int i = t; i < SLOTS; i += NT) {
    if (i < KTOP) {
      int q = idx[i];
      sel[bh * SLOTS + i] = q;
      slotmap[bh * L_DIM + q] = i;
    } else {
      sel[bh * SLOTS + i] = -1;
    }
  }
}

__device__ void attn_body(const bf16_t* Qhi, const bf16_t* Khi, const bf16_t* VThi,
                          const int* sel, float* Ol, bf16_t* Oo,
                          int bx, bf16_t* sPh) {
  const int bh = bx & 31;
  const int t2 = bx >> 5;
  const int qc = t2 % 7;
  const int ks = t2 / 7;
  const int b = bh >> 4, h = bh & 15;
  const int wave = threadIdx.x >> 6;
  const int lane = threadIdx.x & 63;
  const int lm = lane & 15, quad = lane >> 4;

  const int qbase = qc * 64 + wave * 16;
  const int qi = sel[bh * SLOTS + qbase + lm];
  const size_t qo = ((size_t)(b * L_DIM + (qi >= 0 ? qi : 0))) * D_DIM + h * 64;
  const bf16x8 qa0 = *reinterpret_cast<const bf16x8*>(&Qhi[qo + quad * 8]);
  const bf16x8 qa1 = *reinterpret_cast<const bf16x8*>(&Qhi[qo + 32 + quad * 8]);

  const f32x4 vzero = {0.f, 0.f, 0.f, 0.f};
  float l_l[4] = {0.f, 0.f, 0.f, 0.f};
  f32x4 o[4];
  #pragma unroll
  for (int ni = 0; ni < 4; ++ni) o[ni] = vzero;

  const float scale = 0.125f;
  const size_t kbase = (size_t)(b * L_DIM) * D_DIM + h * 64;
  const int key0 = ks * KCHUNK;

  for (int kt = 0; kt < KCHUNK; kt += 32) {
    size_t kr0 = kbase + (size_t)(key0 + kt + lm) * D_DIM;
    size_t kr1 = kbase + (size_t)(key0 + kt + 16 + lm) * D_DIM;
    bf16x8 kb0 = *reinterpret_cast<const bf16x8*>(&Khi[kr0 + quad * 8]);
    bf16x8 kb1 = *reinterpret_cast<const bf16x8*>(&Khi[kr0 + 32 + quad * 8]);
    bf16x8 kb2 = *reinterpret_cast<const bf16x8*>(&Khi[kr1 + quad * 8]);
    bf16x8 kb3 = *reinterpret_cast<const bf16x8*>(&Khi[kr1 + 32 + quad * 8]);
    bf16x8 vbh[4];
    #pragma unroll
    for (int ni = 0; ni < 4; ++ni) {
      size_t vo = ((size_t)(b * D_DIM + h * 64 + ni * 16 + lm)) * L_DIM + key0 + kt + quad * 8;
      vbh[ni] = *reinterpret_cast<const bf16x8*>(&VThi[vo]);
    }
    f32x4 s0 = vzero, s1 = vzero;
    s0 = __builtin_amdgcn_mfma_f32_16x16x32_bf16(qa0, kb0, s0, 0, 0, 0);
    s0 = __builtin_amdgcn_mfma_f32_16x16x32_bf16(qa1, kb1, s0, 0, 0, 0);
    s1 = __builtin_amdgcn_mfma_f32_16x16x32_bf16(qa0, kb2, s1, 0, 0, 0);
    s1 = __builtin_amdgcn_mfma_f32_16x16x32_bf16(qa1, kb3, s1, 0, 0, 0);
    #pragma unroll
    for (int r = 0; r < 4; ++r) {
      float p0 = __expf(s0[r] * scale);
      float p1 = __expf(s1[r] * scale);
      l_l[r] += p0 + p1;
      sPh[wave * 640 + (quad * 4 + r) * 40 + lm]      = (bf16_t)p0;
      sPh[wave * 640 + (quad * 4 + r) * 40 + 16 + lm] = (bf16_t)p1;
    }
    bf16x8 pah = *reinterpret_cast<const bf16x8*>(&sPh[wave * 640 + lm * 40 + quad * 8]);
    #pragma unroll
    for (int ni = 0; ni < 4; ++ni)
      o[ni] = __builtin_amdgcn_mfma_f32_16x16x32_bf16(pah, vbh[ni], o[ni], 0, 0, 0);
  }

  #pragma unroll
  for (int r = 0; r < 4; ++r) {
    l_l[r] += __shfl_xor(l_l[r], 1);
    l_l[r] += __shfl_xor(l_l[r], 2);
    l_l[r] += __shfl_xor(l_l[r], 4);
    l_l[r] += __shfl_xor(l_l[r], 8);
  }

  #pragma unroll
  for (int r = 0; r < 4; ++r) {
    int slot = qbase + quad * 4 + r;
    int s2 = sel[bh * SLOTS + slot];
    if (s2 >= 0) {
      size_t gs = (size_t)(bh * SLOTS + slot) * KSPLIT + ks;
      if (lm == 0) Ol[gs] = l_l[r];
      #pragma unroll
      for (int ni = 0; ni < 4; ++ni)
        Oo[gs * 64 + ni * 16 + lm] = (bf16_t)o[ni][r];
    }
  }
}

__device__ void finish_body(const bf16_t* VThi, const float* Ol, const bf16_t* Oo,
                            const int* slotmap, bf16_t* AOhi,
                            int j, float* smean) {
  const int bh = j & 31;
  const int lbase = (j >> 5) * 256;
  const int b = bh >> 4, h = bh & 15;
  const int t = threadIdx.x;
  {
    const int hd = t >> 2, part = t & 3;
    size_t base = ((size_t)(b * D_DIM + h * 64 + hd)) * L_DIM;
    float s = 0.f;
    for (int l0 = part * 512; l0 < part * 512 + 512; l0 += 8) {
      bf16x8 vh = *reinterpret_cast<const bf16x8*>(&VThi[base + l0]);
      #pragma unroll
      for (int jj = 0; jj < 8; ++jj) s += (float)vh[jj];
    }
    s += __shfl_xor(s, 1);
    s += __shfl_xor(s, 2);
    if (part == 0) smean[hd] = s * (1.0f / (float)L_DIM);
  }
  __syncthreads();
  for (int i = t; i < 256 * 64; i += 256) {
    int l = lbase + (i >> 6), hd = i & 63;
    int slot = slotmap[bh * L_DIM + l];
    float val;
    if (slot < 0) {
      val = smean[hd];
    } else {
      size_t gs = (size_t)(bh * SLOTS + slot) * KSPLIT;
      float L = 0.f, ov = 0.f;
      #pragma unroll
      for (int s2 = 0; s2 < KSPLIT; ++s2) {
        L  += Ol[gs + s2];
        ov += (float)Oo[(gs + s2) * 64 + hd];
      }
      val = ov / L;
    }
    AOhi[((size_t)(b * L_DIM + l)) * D_DIM + h * 64 + hd] = (bf16_t)val;
  }
}

__device__ void gemm_out_body(const bf16_t* Ahi, const bf16_t* Wob,
                              const float* bias, float* C, int j, char* smem_raw) {
  const int n0   = (j & 7) * 128;
  const int row0 = (j >> 3) * 64;

  bf16_t* sA = (bf16_t*)smem_raw;
  bf16_t* sB = (bf16_t*)(smem_raw + 4096);

  const int tid  = threadIdx.x;
  const int lane = tid & 63;
  const int wave = tid >> 6;
  const int wr = wave >> 1, wc = wave & 1;
  const int lm = lane & 15, quad = lane >> 4;

  const f32x4 vzero = {0.f, 0.f, 0.f, 0.f};
  f32x4 acc[2][4];
  #pragma unroll
  for (int mi = 0; mi < 2; ++mi)
    #pragma unroll
    for (int ni = 0; ni < 4; ++ni) acc[mi][ni] = vzero;

  for (int k0 = 0; k0 < D_DIM; k0 += 32) {
    __syncthreads();
    STAGE_TILE64(Ahi + (size_t)row0 * D_DIM + k0, sA);
    STAGE_TILE128(Wob + (size_t)n0 * D_DIM + k0, sB);
    __syncthreads();
    bf16x8 af[2], bfr[4];
    #pragma unroll
    for (int mi = 0; mi < 2; ++mi)
      af[mi] = *reinterpret_cast<const bf16x8*>(&sA[(wr * 32 + mi * 16 + lm) * 32 + quad * 8]);
    #pragma unroll
    for (int ni = 0; ni < 4; ++ni)
      bfr[ni] = *reinterpret_cast<const bf16x8*>(&sB[(wc * 64 + ni * 16 + lm) * 32 + quad * 8]);
    #pragma unroll
    for (int mi = 0; mi < 2; ++mi)
      #pragma unroll
      for (int ni = 0; ni < 4; ++ni)
        acc[mi][ni] = __builtin_amdgcn_mfma_f32_16x16x32_bf16(af[mi], bfr[ni], acc[mi][ni], 0, 0, 0);
  }

  float bvv[4];
  #pragma unroll
  for (int ni = 0; ni < 4; ++ni) bvv[ni] = bias[n0 + wc * 64 + ni * 16 + lm];
  #pragma unroll
  for (int mi = 0; mi < 2; ++mi)
    #pragma unroll
    for (int r = 0; r < 4; ++r) {
      int row = row0 + wr * 32 + mi * 16 + quad * 4 + r;
      #pragma unroll
      for (int ni = 0; ni < 4; ++ni)
        C[(size_t)row * D_DIM + n0 + wc * 64 + ni * 16 + lm] = acc[mi][ni][r] + bvv[ni];
    }
}

// ===========================================================================
// Fused cooperative kernel — 6 stages, 5 grid.syncs, zero launch gaps.
// ===========================================================================
__global__ __launch_bounds__(256, 2) void fused_kernel(FusedArgs a) {
  __shared__ __align__(16) char smem_raw[32768];
  cg::grid_group grid = cg::this_grid();

  {
    const int TOT = (M_DIM * D_DIM) / 4 + D_DIM * D_DIM;  // XV + 4*WV
    for (int i = blockIdx.x * 256 + threadIdx.x; i < TOT; i += NBLK * 256)
      prep_body(a.x, a.Wq, a.Wk, a.Wv, a.Wo, a.xhi, a.xlo,
                a.Wqhi, a.Wqlo, a.Wkb, a.Wvb, a.Wob, i);
  }
  grid.sync();

  if (blockIdx.x < 256) {
    gemm_body(a.xhi, a.xlo, a.Wqhi, a.Wqlo, a.Wkb, a.Wvb, a.bq, a.bk, a.bv,
              a.Qhi, a.Khi, a.VThi, a.norms, 0, blockIdx.x, smem_raw);
  } else {
    gemm_body(a.xhi, a.xlo, a.Wqhi, a.Wqlo, a.Wkb, a.Wvb, a.bq, a.bk, a.bv,
              a.Qhi, a.Khi, a.VThi, a.norms, 1, blockIdx.x & 255, smem_raw);
    gemm_body(a.xhi, a.xlo, a.Wqhi, a.Wqlo, a.Wkb, a.Wvb, a.bq, a.bk, a.bv,
              a.Qhi, a.Khi, a.VThi, a.norms, 2, blockIdx.x & 255, smem_raw);
  }
  grid.sync();

  if (blockIdx.x < 32)
    topk_body(a.norms, a.sel, a.slotmap, blockIdx.x,
              (float*)smem_raw, (int*)(smem_raw + 8192), 256);
  grid.sync();

  for (int j = blockIdx.x; j < 32 * 7 * KSPLIT; j += NBLK)
    attn_body(a.Qhi, a.Khi, a.VThi, a.sel, a.Ol, a.Oo, j, (bf16_t*)smem_raw);
  grid.sync();

  if (blockIdx.x < 256)
    finish_body(a.VThi, a.Ol, a.Oo, a.slotmap, a.AOhi, blockIdx.x, (float*)smem_raw);
  grid.sync();

  gemm_out_body(a.AOhi, a.Wob, a.bo, a.out, blockIdx.x, smem_raw);
}

// ===========================================================================
// Fallback wrappers (exact R8-proven pipeline, reusing the same bodies).
// ===========================================================================
__global__ __launch_bounds__(256) void prep_kernel_f(FusedArgs a) {
  int i = blockIdx.x * 256 + threadIdx.x;
  prep_body(a.x, a.Wq, a.Wk, a.Wv, a.Wo, a.xhi, a.xlo,
            a.Wqhi, a.Wqlo, a.Wkb, a.Wvb, a.Wob, i);
}

__global__ __launch_bounds__(256) void gemm_qkv_f(FusedArgs a) {
  __shared__ __align__(16) char smem_raw[32768];
  gemm_body(a.xhi, a.xlo, a.Wqhi, a.Wqlo, a.Wkb, a.Wvb, a.bq, a.bk, a.bv,
            a.Qhi, a.Khi, a.VThi, a.norms, blockIdx.z,
            blockIdx.y * 8 + blockIdx.x, smem_raw);
}

__global__ __launch_bounds__(1024) void topk_kernel_f(FusedArgs a) {
  __shared__ __align__(16) float val[L_DIM];
  __shared__ __align__(16) int   idx[L_DIM];
  topk_body(a.norms, a.sel, a.slotmap, blockIdx.x, val, idx, 1024);
}

__global__ __launch_bounds__(256) void attn_kernel_f(FusedArgs a) {
  __shared__ __align__(16) bf16_t sPh[4 * 640];
  attn_body(a.Qhi, a.Khi, a.VThi, a.sel, a.Ol, a.Oo, blockIdx.x, sPh);
}

__global__ __launch_bounds__(256) void finish_kernel_f(FusedArgs a) {
  __shared__ float smean[64];
  finish_body(a.VThi, a.Ol, a.Oo, a.slotmap, a.AOhi,
              blockIdx.y * 32 + blockIdx.x, smean);
}

__global__ __launch_bounds__(256) void gemm_out_f(FusedArgs a) {
  __shared__ __align__(16) char smem_raw[12288];
  gemm_out_body(a.AOhi, a.Wob, a.bo, a.out, blockIdx.y * 8 + blockIdx.x, smem_raw);
}

// ===========================================================================
extern "C" void kernel_launch(void* const* d_in, const int* in_sizes, int n_in,
                              void* d_out, int out_size, void* d_ws, size_t ws_size,
                              hipStream_t stream) {
  const size_t MB = 1u << 20;
  const size_t KB = 1u << 10;
  char* ws = (char*)d_ws;

  FusedArgs fa;
  fa.x  = (const float*)d_in[0];
  fa.Wq = (const float*)d_in[1];
  fa.bq = (const float*)d_in[2];
  fa.Wk = (const float*)d_in[3];
  fa.bk = (const float*)d_in[4];
  fa.Wv = (const float*)d_in[5];
  fa.bv = (const float*)d_in[6];
  fa.Wo = (const float*)d_in[7];
  fa.bo = (const float*)d_in[8];
  fa.Qhi  = (bf16_t*)(ws);                    // 8 MB; aliased as AOhi later
  fa.VThi = (bf16_t*)(ws + 8 * MB);           // 8 MB
  fa.xhi  = (bf16_t*)(ws + 16 * MB);          // 8 MB -+ dead after gemm;
  fa.xlo  = (bf16_t*)(ws + 24 * MB);          // 8 MB -+ region reused for Oo
  fa.Oo   = (bf16_t*)(ws + 16 * MB);          // 14.7 MB, aliases xhi/xlo
  fa.Wqhi = (bf16_t*)(ws + 32 * MB);
  fa.Wqlo = (bf16_t*)(ws + 34 * MB);
  fa.Wkb  = (bf16_t*)(ws + 36 * MB);
  fa.Wvb  = (bf16_t*)(ws + 38 * MB);
  fa.Wob  = (bf16_t*)(ws + 40 * MB);
  fa.norms   = (float*)(ws + 42 * MB);            // 256 KB
  fa.sel     = (int*)(ws + 42 * MB + 320 * KB);   // 57 KB
  fa.Ol      = (float*)(ws + 42 * MB + 384 * KB); // 448 KB
  fa.slotmap = (int*)(ws + 42 * MB + 832 * KB);   // 256 KB
  fa.AOhi = fa.Qhi;
  fa.Khi  = (bf16_t*)d_out;                   // dead until gemm_out rewrites
  fa.out  = (float*)d_out;

  // Gate the cooperative path on actual device occupancy (pure host queries —
  // deterministic and graph-capture-safe). R10's silent failure was almost
  // certainly hipErrorCooperativeLaunchTooLarge from an unchecked launch.
  bool use_coop = false;
  int dev = 0;
  if (hipGetDevice(&dev) == hipSuccess) {
    int coop = 0, ncu = 0, maxblk = 0;
    hipDeviceGetAttribute(&coop, hipDeviceAttributeCooperativeLaunch, dev);
    hipDeviceGetAttribute(&ncu, hipDeviceAttributeMultiprocessorCount, dev);
    if (coop &&
        hipOccupancyMaxActiveBlocksPerMultiprocessor(&maxblk, fused_kernel, 256, 0)
            == hipSuccess &&
        maxblk * ncu >= NBLK)
      use_coop = true;
  }

  if (use_coop) {
    void* kargs[] = { (void*)&fa };
    hipError_t e = hipLaunchCooperativeKernel((const void*)fused_kernel,
                                              dim3(NBLK), dim3(256), kargs, 0, stream);
    if (e == hipSuccess) return;
    (void)hipGetLastError();   // clear sticky error, fall through
  }

  // Fallback: proven R8 multi-kernel pipeline (305.6 us, absmax 1.22e-3).
  dim3 blk(256);
  prep_kernel_f<<<dim3(8192), blk, 0, stream>>>(fa);
  gemm_qkv_f<<<dim3(8, 32, 3), blk, 0, stream>>>(fa);
  topk_kernel_f<<<dim3(32), dim3(1024), 0, stream>>>(fa);
  attn_kernel_f<<<dim3(32 * 7 * KSPLIT), blk, 0, stream>>>(fa);
  finish_kernel_f<<<dim3(32, 8), blk, 0, stream>>>(fa);
  gemm_out_f<<<dim3(8, 64), blk, 0, stream>>>(fa);
}